// Round 8
// baseline (500.797 us; speedup 1.0000x reference)
//
#include <hip/hip_runtime.h>

// ---------------- constants ----------------
#define NTOP   4096
#define SORTN  8192
#define CONF_T 0.5f
#define IOU_T  0.6f

// ws layout (bytes)
#define HIST_OFF   0          // 2048 * u32 = 8 KB
#define CUT_OFF    8192       // int
#define CNT_OFF    8196       // u32
#define COMP_OFF   16384      // 8192 * u64 = 64 KB  (zeroed)
#define MEMSET_BYTES 81920    // covers hist+cut+cnt+comp
#define KEYS_OFF   131072     // 200000 * u64 = 1.6 MB
#define TB_OFF     2097152    // 4096 * float4 = 64 KB
#define TC_OFF     2162688    // 4096 * float  = 16 KB
#define VALID_OFF  2179072    // 64 * u64
#define KEEP_OFF   2179584    // 64 * u64
#define MASK_OFF   4194304    // 4096*64*u64 = 2 MB

typedef unsigned long long u64;
typedef unsigned int u32;

// K1: build keys + histogram of top-20 bits of score (valid only)
__global__ void k_keys(const float* __restrict__ confs, u64* __restrict__ keys,
                       u32* __restrict__ hist, int n) {
    int i = blockIdx.x * 256 + threadIdx.x;
    if (i >= n) return;
    float s = confs[i];
    if (s >= CONF_T) {
        u32 u = __float_as_uint(s);              // positive -> bits monotone
        keys[i] = ((u64)u << 32) | (u32)(~i);    // tie: lower index wins
        int bin = (int)(u >> 12) - 0x3F000;      // [0.5,1) -> [0,2047]
        bin = bin < 0 ? 0 : (bin > 2047 ? 2047 : bin);
        atomicAdd(&hist[bin], 1u);
    } else {
        keys[i] = 0ull;
    }
}

// K2: find cut bucket (largest b with suffix-count >= NTOP), single block
__global__ __launch_bounds__(256) void k_findcut(const u32* __restrict__ hist,
                                                 int* __restrict__ cut) {
    __shared__ u32 ch[256];
    int t = threadIdx.x;
    u32 h[8]; u32 s = 0;
#pragma unroll
    for (int k = 0; k < 8; ++k) { h[k] = hist[t * 8 + k]; s += h[k]; }
    ch[t] = s;
    __syncthreads();
    // inclusive suffix scan of chunk sums
    for (int off = 1; off < 256; off <<= 1) {
        u32 v = ch[t];
        u32 add = (t + off < 256) ? ch[t + off] : 0u;
        __syncthreads();
        ch[t] = v + add;
        __syncthreads();
    }
    u32 incl = ch[t];            // sum over bins >= t*8
    u32 above = incl - s;        // sum over bins >= (t+1)*8
    if (above < NTOP && incl >= NTOP) {
        u32 cum = above; int c = 0;
        for (int k = 7; k >= 0; --k) {
            cum += h[k];
            if (cum >= NTOP) { c = t * 8 + k; break; }
        }
        *cut = c;
    }
    if (t == 0 && ch[0] < NTOP) *cut = 0;   // fewer than NTOP valid: take all
}

// K3: compact candidates with bucket >= cut
__global__ void k_compact(const u64* __restrict__ keys, const int* __restrict__ cut,
                          u64* __restrict__ comp, u32* __restrict__ counter, int n) {
    int i = blockIdx.x * 256 + threadIdx.x;
    if (i >= n) return;
    u64 key = keys[i];
    if (!key) return;
    int bin = (int)(u32)(key >> 44) - 0x3F000;
    bin = bin < 0 ? 0 : (bin > 2047 ? 2047 : bin);
    if (bin >= *cut) {
        u32 p = atomicAdd(counter, 1u);
        if (p < SORTN) comp[p] = key;
    }
}

// K4: bitonic sort SORTN u64 keys descending, single block, 64KB LDS.
// Epilogue (fused, was k_gather): gather top boxes/scores, build valid bitmask.
__global__ __launch_bounds__(1024) void k_sort(const u64* __restrict__ comp,
                                               const float4* __restrict__ boxes,
                                               float4* __restrict__ tb,
                                               float* __restrict__ tc,
                                               u64* __restrict__ validmask) {
    __shared__ u64 sm[SORTN];
    int t = threadIdx.x;
    for (int i = t; i < SORTN; i += 1024) sm[i] = comp[i];
    __syncthreads();
    for (int k = 2; k <= SORTN; k <<= 1) {
        for (int j = k >> 1; j > 0; j >>= 1) {
            for (int i = t; i < SORTN; i += 1024) {
                int ixj = i ^ j;
                if (ixj > i) {
                    u64 a = sm[i], b = sm[ixj];
                    bool sw = ((i & k) == 0) ? (a < b) : (a > b);  // descending
                    if (sw) { sm[i] = b; sm[ixj] = a; }
                }
            }
            __syncthreads();
        }
    }
    // fused gather: first NTOP sorted keys -> boxes/scores/valid bitmask
    for (int base = 0; base < NTOP; base += 1024) {
        int k = base + t;
        u64 key = sm[k];
        float score = __uint_as_float((u32)(key >> 32));
        bool valid = (key != 0ull) && (score >= CONF_T);
        float4 b = make_float4(0.f, 0.f, 0.f, 0.f);
        if (valid) {
            u32 idx = ~(u32)(key & 0xFFFFFFFFull);
            b = boxes[idx];
        }
        tb[k] = b;
        tc[k] = score;
        u64 bal = __ballot(valid);
        if ((t & 63) == 0) validmask[k >> 6] = bal;
    }
}

// K6: suppression bitmask matrix: mask[row][w] bit j = iou(row, w*64+j) > T
__global__ __launch_bounds__(256) void k_mask(const float4* __restrict__ tb,
                                              u64* __restrict__ mask) {
    __shared__ float4 cb[64];
    __shared__ float  ca[64];
    int w = blockIdx.x;           // word 0..63
    int t = threadIdx.x;
    if (t < 64) {
        float4 b = tb[w * 64 + t];
        cb[t] = b;
        ca[t] = fmaxf(b.z - b.x, 0.f) * fmaxf(b.w - b.y, 0.f);
    }
    __syncthreads();
    int row = blockIdx.y * 256 + t;
    float4 rb = tb[row];
    float ra = fmaxf(rb.z - rb.x, 0.f) * fmaxf(rb.w - rb.y, 0.f);
    u64 m = 0;
#pragma unroll 8
    for (int j = 0; j < 64; ++j) {
        float4 c = cb[j];
        float lx = fmaxf(rb.x, c.x), ly = fmaxf(rb.y, c.y);
        float rx = fminf(rb.z, c.z), ry = fminf(rb.w, c.w);
        float iw = fmaxf(rx - lx, 0.f), ih = fmaxf(ry - ly, 0.f);
        float inter = iw * ih;
        float iou = inter / (ra + ca[j] - inter + 1e-9f);
        if (iou > IOU_T) m |= (1ull << j);
    }
    mask[(size_t)row * 64 + w] = m;
}

// 64-entry macro expander (named prefetch registers p0..p63)
#define L64(X) X(0) X(1) X(2) X(3) X(4) X(5) X(6) X(7) X(8) X(9) X(10) X(11) \
  X(12) X(13) X(14) X(15) X(16) X(17) X(18) X(19) X(20) X(21) X(22) X(23) \
  X(24) X(25) X(26) X(27) X(28) X(29) X(30) X(31) X(32) X(33) X(34) X(35) \
  X(36) X(37) X(38) X(39) X(40) X(41) X(42) X(43) X(44) X(45) X(46) X(47) \
  X(48) X(49) X(50) X(51) X(52) X(53) X(54) X(55) X(56) X(57) X(58) X(59) \
  X(60) X(61) X(62) X(63)

// K7: serial greedy NMS scan — single wave, lane w owns suppression word w.
// Prefetch state is 64 NAMED u64 registers (p0..p63), not an array: rule-#20
// sibling — SROA runs before unrolling, so pragma-unrolled array indexing
// still lands in scratch (r6/r7: VGPR=56, 109 cy/iter scratch round-trip).
// Named scalars are mem2reg-promoted unconditionally. Depth 64 == w-block
// size: iteration w consumes rows w*64+d and prefetches rows (w+1)*64+d,
// so bit = d is a literal and one full w-iter of compute hides HBM latency.
__global__ __launch_bounds__(64, 1) void k_nms(const u64* __restrict__ mask,
                                               const u64* __restrict__ validmask,
                                               u64* __restrict__ keep) {
    int lane = threadIdx.x;
    u64 mysup = ~validmask[lane];
    u64 mykeep = 0;

#define DECLP(i) u64 p##i = mask[(size_t)(i) * 64 + lane];
    L64(DECLP)
#undef DECLP

    for (int w = 0; w < 64; ++w) {
        // broadcast word w of the suppression state to scalar regs
        u32 clo = (u32)__builtin_amdgcn_readlane((int)(u32)mysup, w);
        u32 chi = (u32)__builtin_amdgcn_readlane((int)(u32)(mysup >> 32), w);
        u64 cur = ((u64)chi << 32) | clo;
        u64 blockkeep = 0;
        int wn = (w < 63) ? (w + 1) : w;
        const u64* nrow = mask + (size_t)wn * 4096 + lane;  // row (wn*64+d), word lane

#define STEPD(i) { \
        u64 rowv = p##i;                      /* mask[w*64+i][lane] */ \
        p##i = nrow[(size_t)(i) * 64];        /* prefetch next block (off-chain) */ \
        u32 dlo = (u32)__builtin_amdgcn_readlane((int)(u32)rowv, w); \
        u32 dhi = (u32)__builtin_amdgcn_readlane((int)(u32)(rowv >> 32), w); \
        u64 dwv = ((u64)dhi << 32) | dlo;     /* diagonal word mask[i][w] */ \
        bool is_keep = ((cur >> (i)) & 1ull) == 0ull; \
        u64 m = is_keep ? ~0ull : 0ull;       /* uniform -> s_cselect_b64 */ \
        cur |= dwv & m;                       /* scalar chain */ \
        mysup |= rowv & m;                    /* vector accumulate */ \
        blockkeep |= is_keep ? (1ull << (i)) : 0ull; \
    }
        L64(STEPD)
#undef STEPD

        if (lane == w) mykeep = blockkeep;
    }
    keep[lane] = mykeep;
}

// K8: write output [4096,5], zero suppressed rows
__global__ void k_out(const float4* __restrict__ tb, const float* __restrict__ tc,
                      const u64* __restrict__ keep, float* __restrict__ out) {
    int k = blockIdx.x * 256 + threadIdx.x;
    bool kp = (keep[k >> 6] >> (k & 63)) & 1ull;
    float4 b = tb[k];
    float c = tc[k];
    float* o = out + (size_t)k * 5;
    o[0] = kp ? b.x : 0.f;
    o[1] = kp ? b.y : 0.f;
    o[2] = kp ? b.z : 0.f;
    o[3] = kp ? b.w : 0.f;
    o[4] = kp ? c : 0.f;
}

extern "C" void kernel_launch(void* const* d_in, const int* in_sizes, int n_in,
                              void* d_out, int out_size, void* d_ws, size_t ws_size,
                              hipStream_t stream) {
    const float4* boxes = (const float4*)d_in[0];   // [1,N,4] f32
    const float*  confs = (const float*)d_in[1];    // [1,N]   f32
    float* out = (float*)d_out;                     // [4096,5] f32
    char* ws = (char*)d_ws;
    int n = in_sizes[1];

    u32* hist    = (u32*)(ws + HIST_OFF);
    int* cut     = (int*)(ws + CUT_OFF);
    u32* counter = (u32*)(ws + CNT_OFF);
    u64* comp    = (u64*)(ws + COMP_OFF);
    u64* keys    = (u64*)(ws + KEYS_OFF);
    float4* tb   = (float4*)(ws + TB_OFF);
    float*  tc   = (float*)(ws + TC_OFF);
    u64* validm  = (u64*)(ws + VALID_OFF);
    u64* keep    = (u64*)(ws + KEEP_OFF);
    u64* mask    = (u64*)(ws + MASK_OFF);

    hipMemsetAsync(ws, 0, MEMSET_BYTES, stream);
    k_keys<<<(n + 255) / 256, 256, 0, stream>>>(confs, keys, hist, n);
    k_findcut<<<1, 256, 0, stream>>>(hist, cut);
    k_compact<<<(n + 255) / 256, 256, 0, stream>>>(keys, cut, comp, counter, n);
    k_sort<<<1, 1024, 0, stream>>>(comp, boxes, tb, tc, validm);
    k_mask<<<dim3(64, 16), 256, 0, stream>>>(tb, mask);
    k_nms<<<1, 64, 0, stream>>>(mask, validm, keep);
    k_out<<<16, 256, 0, stream>>>(tb, tc, keep, out);
}

// Round 9
// 468.946 us; speedup vs baseline: 1.0679x; 1.0679x over previous
//
#include <hip/hip_runtime.h>

// ---------------- constants ----------------
#define NTOP   4096
#define SORTN  8192
#define CONF_T 0.5f
#define IOU_T  0.6f

// ws layout (bytes)
#define HIST_OFF   0          // 2048 * u32 = 8 KB
#define CUT_OFF    8192       // int
#define CNT_OFF    8196       // u32
#define COMP_OFF   16384      // 8192 * u64 = 64 KB  (zeroed)
#define MEMSET_BYTES 81920    // covers hist+cut+cnt+comp
#define KEYS_OFF   131072     // 200000 * u64 = 1.6 MB
#define TB_OFF     2097152    // 4096 * float4 = 64 KB
#define TC_OFF     2162688    // 4096 * float  = 16 KB
#define VALID_OFF  2179072    // 64 * u64
#define KEEP_OFF   2179584    // 64 * u64
#define MASK_OFF   4194304    // 4096*64*u64 = 2 MB

typedef unsigned long long u64;
typedef unsigned int u32;

// K1: build keys + histogram of top-20 bits of score (valid only)
__global__ void k_keys(const float* __restrict__ confs, u64* __restrict__ keys,
                       u32* __restrict__ hist, int n) {
    int i = blockIdx.x * 256 + threadIdx.x;
    if (i >= n) return;
    float s = confs[i];
    if (s >= CONF_T) {
        u32 u = __float_as_uint(s);              // positive -> bits monotone
        keys[i] = ((u64)u << 32) | (u32)(~i);    // tie: lower index wins
        int bin = (int)(u >> 12) - 0x3F000;      // [0.5,1) -> [0,2047]
        bin = bin < 0 ? 0 : (bin > 2047 ? 2047 : bin);
        atomicAdd(&hist[bin], 1u);
    } else {
        keys[i] = 0ull;
    }
}

// K2: find cut bucket (largest b with suffix-count >= NTOP), single block
__global__ __launch_bounds__(256) void k_findcut(const u32* __restrict__ hist,
                                                 int* __restrict__ cut) {
    __shared__ u32 ch[256];
    int t = threadIdx.x;
    u32 h[8]; u32 s = 0;
#pragma unroll
    for (int k = 0; k < 8; ++k) { h[k] = hist[t * 8 + k]; s += h[k]; }
    ch[t] = s;
    __syncthreads();
    // inclusive suffix scan of chunk sums
    for (int off = 1; off < 256; off <<= 1) {
        u32 v = ch[t];
        u32 add = (t + off < 256) ? ch[t + off] : 0u;
        __syncthreads();
        ch[t] = v + add;
        __syncthreads();
    }
    u32 incl = ch[t];            // sum over bins >= t*8
    u32 above = incl - s;        // sum over bins >= (t+1)*8
    if (above < NTOP && incl >= NTOP) {
        u32 cum = above; int c = 0;
        for (int k = 7; k >= 0; --k) {
            cum += h[k];
            if (cum >= NTOP) { c = t * 8 + k; break; }
        }
        *cut = c;
    }
    if (t == 0 && ch[0] < NTOP) *cut = 0;   // fewer than NTOP valid: take all
}

// K3: compact candidates with bucket >= cut
__global__ void k_compact(const u64* __restrict__ keys, const int* __restrict__ cut,
                          u64* __restrict__ comp, u32* __restrict__ counter, int n) {
    int i = blockIdx.x * 256 + threadIdx.x;
    if (i >= n) return;
    u64 key = keys[i];
    if (!key) return;
    int bin = (int)(u32)(key >> 44) - 0x3F000;
    bin = bin < 0 ? 0 : (bin > 2047 ? 2047 : bin);
    if (bin >= *cut) {
        u32 p = atomicAdd(counter, 1u);
        if (p < SORTN) comp[p] = key;
    }
}

// K4: bitonic sort SORTN u64 keys descending, single block, 64KB LDS.
// Epilogue (fused, was k_gather): gather top boxes/scores, build valid bitmask.
__global__ __launch_bounds__(1024) void k_sort(const u64* __restrict__ comp,
                                               const float4* __restrict__ boxes,
                                               float4* __restrict__ tb,
                                               float* __restrict__ tc,
                                               u64* __restrict__ validmask) {
    __shared__ u64 sm[SORTN];
    int t = threadIdx.x;
    for (int i = t; i < SORTN; i += 1024) sm[i] = comp[i];
    __syncthreads();
    for (int k = 2; k <= SORTN; k <<= 1) {
        for (int j = k >> 1; j > 0; j >>= 1) {
            for (int i = t; i < SORTN; i += 1024) {
                int ixj = i ^ j;
                if (ixj > i) {
                    u64 a = sm[i], b = sm[ixj];
                    bool sw = ((i & k) == 0) ? (a < b) : (a > b);  // descending
                    if (sw) { sm[i] = b; sm[ixj] = a; }
                }
            }
            __syncthreads();
        }
    }
    // fused gather: first NTOP sorted keys -> boxes/scores/valid bitmask
    for (int base = 0; base < NTOP; base += 1024) {
        int k = base + t;
        u64 key = sm[k];
        float score = __uint_as_float((u32)(key >> 32));
        bool valid = (key != 0ull) && (score >= CONF_T);
        float4 b = make_float4(0.f, 0.f, 0.f, 0.f);
        if (valid) {
            u32 idx = ~(u32)(key & 0xFFFFFFFFull);
            b = boxes[idx];
        }
        tb[k] = b;
        tc[k] = score;
        u64 bal = __ballot(valid);
        if ((t & 63) == 0) validmask[k >> 6] = bal;
    }
}

// K6: suppression bitmask matrix: mask[row][w] bit j = iou(row, w*64+j) > T
__global__ __launch_bounds__(256) void k_mask(const float4* __restrict__ tb,
                                              u64* __restrict__ mask) {
    __shared__ float4 cb[64];
    __shared__ float  ca[64];
    int w = blockIdx.x;           // word 0..63
    int t = threadIdx.x;
    if (t < 64) {
        float4 b = tb[w * 64 + t];
        cb[t] = b;
        ca[t] = fmaxf(b.z - b.x, 0.f) * fmaxf(b.w - b.y, 0.f);
    }
    __syncthreads();
    int row = blockIdx.y * 256 + t;
    float4 rb = tb[row];
    float ra = fmaxf(rb.z - rb.x, 0.f) * fmaxf(rb.w - rb.y, 0.f);
    u64 m = 0;
#pragma unroll 8
    for (int j = 0; j < 64; ++j) {
        float4 c = cb[j];
        float lx = fmaxf(rb.x, c.x), ly = fmaxf(rb.y, c.y);
        float rx = fminf(rb.z, c.z), ry = fminf(rb.w, c.w);
        float iw = fmaxf(rx - lx, 0.f), ih = fmaxf(ry - ly, 0.f);
        float inter = iw * ih;
        float iou = inter / (ra + ca[j] - inter + 1e-9f);
        if (iou > IOU_T) m |= (1ull << j);
    }
    mask[(size_t)row * 64 + w] = m;
}

// ---- K7 consumer macros: batched LDS reads + scalar-chain step (r8-validated
// bit logic, unchanged). All rows/bits are compile-time literals. ----
#define RD(p, base) \
    p##0 = Bp[(base + 0) * 64 + lane]; p##1 = Bp[(base + 1) * 64 + lane]; \
    p##2 = Bp[(base + 2) * 64 + lane]; p##3 = Bp[(base + 3) * 64 + lane]; \
    p##4 = Bp[(base + 4) * 64 + lane]; p##5 = Bp[(base + 5) * 64 + lane]; \
    p##6 = Bp[(base + 6) * 64 + lane]; p##7 = Bp[(base + 7) * 64 + lane];

#define ST(rv, bit) { \
    u32 dlo = (u32)__builtin_amdgcn_readlane((int)(u32)(rv), w); \
    u32 dhi = (u32)__builtin_amdgcn_readlane((int)(u32)((rv) >> 32), w); \
    u64 dwv = ((u64)dhi << 32) | dlo;   /* diagonal word mask[row][w] */ \
    bool is_keep = ((cur >> (bit)) & 1ull) == 0ull; \
    u64 mm = is_keep ? ~0ull : 0ull;    /* uniform -> s_cselect_b64 */ \
    cur |= dwv & mm;                    /* scalar chain */ \
    mysup |= (rv) & mm;                 /* vector accumulate */ \
    blockkeep |= is_keep ? (1ull << (bit)) : 0ull; }

#define PR(p, base) \
    ST(p##0, base + 0) ST(p##1, base + 1) ST(p##2, base + 2) ST(p##3, base + 3) \
    ST(p##4, base + 4) ST(p##5, base + 5) ST(p##6, base + 6) ST(p##7, base + 7)

// K7: serial greedy NMS — producer/consumer within one 256-thread block.
// r6/r7/r8 all landed at 110-150 cy/step = one memory round-trip per step:
// the compiler collapses any source-level prefetch rotation (WRITE_SIZE=0.5KB
// proved no scratch was involved; VGPR=140 regs didn't help). Fix: hide
// latency with THREAD-level parallelism instead of instruction scheduling —
// waves 1-3 stream mask blocks into a 2x32KB LDS double-buffer; wave 0 scans
// from LDS in 8-row register batches (ds_read issue distance = 1 batch).
__global__ __launch_bounds__(256, 1) void k_nms(const u64* __restrict__ mask,
                                                const u64* __restrict__ validmask,
                                                u64* __restrict__ keep) {
    __shared__ u64 buf[2][64 * 64];     // 2 x 32 KB (one 64-row block each)
    int tid = threadIdx.x;
    int lane = tid & 63;
    int wid = tid >> 6;

    // prologue: all 256 threads fill buf[0] with block 0
    {
        const ulonglong2* src = (const ulonglong2*)mask;
        ulonglong2* dst = (ulonglong2*)buf[0];
        for (int k = tid; k < 2048; k += 256) dst[k] = src[k];
    }

    u64 mysup = 0, mykeep = 0;
    if (wid == 0) mysup = ~validmask[lane];
    __syncthreads();

    for (int b = 0; b < 64; ++b) {
        if (wid != 0) {
            // producers: stage block b+1 into the other buffer
            if (b + 1 < 64) {
                const ulonglong2* src = (const ulonglong2*)(mask + (size_t)(b + 1) * 4096);
                ulonglong2* dst = (ulonglong2*)buf[(b & 1) ^ 1];
                int p = tid - 64;                 // 0..191
                for (int k = p; k < 2048; k += 192) dst[k] = src[k];
            }
        } else {
            // consumer (wave 0): scan 64 rows of block b from buf[b&1]
            const u64* Bp = buf[b & 1];
            int w = b;
            u32 clo = (u32)__builtin_amdgcn_readlane((int)(u32)mysup, w);
            u32 chi = (u32)__builtin_amdgcn_readlane((int)(u32)(mysup >> 32), w);
            u64 cur = ((u64)chi << 32) | clo;
            u64 blockkeep = 0;
            u64 x0, x1, x2, x3, x4, x5, x6, x7;
            u64 y0, y1, y2, y3, y4, y5, y6, y7;
            RD(x, 0)
            RD(y, 8)  PR(x, 0)
            RD(x, 16) PR(y, 8)
            RD(y, 24) PR(x, 16)
            RD(x, 32) PR(y, 24)
            RD(y, 40) PR(x, 32)
            RD(x, 48) PR(y, 40)
            RD(y, 56) PR(x, 48)
            PR(y, 56)
            if (lane == w) mykeep = blockkeep;
        }
        __syncthreads();
    }
    if (wid == 0) keep[lane] = mykeep;
}

// K8: write output [4096,5], zero suppressed rows
__global__ void k_out(const float4* __restrict__ tb, const float* __restrict__ tc,
                      const u64* __restrict__ keep, float* __restrict__ out) {
    int k = blockIdx.x * 256 + threadIdx.x;
    bool kp = (keep[k >> 6] >> (k & 63)) & 1ull;
    float4 b = tb[k];
    float c = tc[k];
    float* o = out + (size_t)k * 5;
    o[0] = kp ? b.x : 0.f;
    o[1] = kp ? b.y : 0.f;
    o[2] = kp ? b.z : 0.f;
    o[3] = kp ? b.w : 0.f;
    o[4] = kp ? c : 0.f;
}

extern "C" void kernel_launch(void* const* d_in, const int* in_sizes, int n_in,
                              void* d_out, int out_size, void* d_ws, size_t ws_size,
                              hipStream_t stream) {
    const float4* boxes = (const float4*)d_in[0];   // [1,N,4] f32
    const float*  confs = (const float*)d_in[1];    // [1,N]   f32
    float* out = (float*)d_out;                     // [4096,5] f32
    char* ws = (char*)d_ws;
    int n = in_sizes[1];

    u32* hist    = (u32*)(ws + HIST_OFF);
    int* cut     = (int*)(ws + CUT_OFF);
    u32* counter = (u32*)(ws + CNT_OFF);
    u64* comp    = (u64*)(ws + COMP_OFF);
    u64* keys    = (u64*)(ws + KEYS_OFF);
    float4* tb   = (float4*)(ws + TB_OFF);
    float*  tc   = (float*)(ws + TC_OFF);
    u64* validm  = (u64*)(ws + VALID_OFF);
    u64* keep    = (u64*)(ws + KEEP_OFF);
    u64* mask    = (u64*)(ws + MASK_OFF);

    hipMemsetAsync(ws, 0, MEMSET_BYTES, stream);
    k_keys<<<(n + 255) / 256, 256, 0, stream>>>(confs, keys, hist, n);
    k_findcut<<<1, 256, 0, stream>>>(hist, cut);
    k_compact<<<(n + 255) / 256, 256, 0, stream>>>(keys, cut, comp, counter, n);
    k_sort<<<1, 1024, 0, stream>>>(comp, boxes, tb, tc, validm);
    k_mask<<<dim3(64, 16), 256, 0, stream>>>(tb, mask);
    k_nms<<<1, 256, 0, stream>>>(mask, validm, keep);
    k_out<<<16, 256, 0, stream>>>(tb, tc, keep, out);
}